// Round 12
// baseline (194.319 us; speedup 1.0000x reference)
//
#include <hip/hip_runtime.h>

#define NN 50000
#define EE 800000
#define FF 64
#define HH 4
#define HF 256          // H*F
#define NEG_SLOPE 0.2f
#define LN_EPS 1e-5f
#define WPACK_N (4 * 8 * 64 * 8)   // 16384 bf16 elements (W B-frags)
#define NTILE (NN / 16)            // 3125 node tiles
#define TROW 264                   // LDS tile row stride (256 + 8 pad)
#define NXCD 8
#define RCAP 32                    // per-XCD replica row = exactly one 64B line
#define SCATB ((EE / 4 + 255) / 256)   // 782 scatter blocks (ILP x4)
#define WPB (WPACK_N / 256)            // 64 wpack blocks
#define ELRB ((NN + 31) / 32)          // 1563 elr blocks

typedef __attribute__((ext_vector_type(8))) short s8v;    // 8 bf16 (4 VGPRs)
typedef __attribute__((ext_vector_type(4))) float f4v;    // 4 fp32 acc

__device__ __forceinline__ unsigned short f32_to_bf16_rne(float x) {
  unsigned int u = __float_as_uint(x);
  unsigned int r = u + 0x7FFFu + ((u >> 16) & 1u);
  return (unsigned short)(r >> 16);
}

// ---------------- Kernel S: alv/arv/outb2 (tiny, 3 blocks) -----------------
// Folded-weight vectors (R6 algebra): alv[hh][kk] = fc_w[kk, hh*64:] . attn_l[hh],
// outb2 = out_b + gat_bias @ out_w. cnt8 zeroing moved to hipMemsetAsync.
__global__ __launch_bounds__(256) void k_small(
    const float* __restrict__ fc_w, const float* __restrict__ attn_l,
    const float* __restrict__ attn_r, const float* __restrict__ gat_bias,
    const float* __restrict__ out_w, const float* __restrict__ out_b,
    float* __restrict__ alv, float* __restrict__ arv,
    float* __restrict__ outb2) {
  const int gid = blockIdx.x * 256 + threadIdx.x;   // < 768
  if (gid < 512) {
    const int hh = (gid >> 6) & 3, kk = gid & 63;
    const float* fw = fc_w + kk * HF + hh * FF;
    const float* at = (gid < 256 ? attn_l : attn_r) + hh * FF;
    float acc = 0.f;
#pragma unroll
    for (int ff = 0; ff < FF; ++ff) acc = fmaf(fw[ff], at[ff], acc);
    (gid < 256 ? alv : arv)[(hh << 6) | kk] = acc;
  } else if (gid < 512 + FF) {
    const int c = gid - 512;                        // 0..63
    float acc = out_b[c];
    for (int k = 0; k < HF; ++k)
      acc = fmaf(gat_bias[k], out_w[(size_t)k * FF + c], acc);
    outb2[c] = acc;
  }
}

// ------- Fused Kernel: scatter (long pole) || wpack fold || elr ------------
// R11 scatter counters: VALUBusy 0.3%, saturates at <=23% occupancy, pinned
// at ~52us = 800K atomics x 64B line / ~950 GB/s (structural floor across
// device-scope/wg-scope/ILP4 -- R6/R10/R11). So OVERLAP the ~15us of
// prep+elr under it: scatter role = 782 blocks (first, <=3/CU leaves ~5/CU
// free), wpack (64) + elr (1563, short streaming) backfill from t=0. This
// fixes R4's fusion failure mode (there the long pole was 3125 blocks that
// filled every slot and queued the short role behind it).
__global__ __launch_bounds__(256) void k_fused(
    const int* __restrict__ src, const int* __restrict__ dst,
    int* __restrict__ cnt8, unsigned short* __restrict__ colp8,
    const float* __restrict__ fc_w, const float* __restrict__ out_w,
    unsigned short* __restrict__ wpack, const float* __restrict__ h,
    const float* __restrict__ alv, const float* __restrict__ arv,
    unsigned short* __restrict__ hb, float* __restrict__ el,
    float* __restrict__ er) {
  const int bid = blockIdx.x;
  if (bid < SCATB) {
    // ---- scatter role: XCD-local padded CSR, 4 edges/thread ----
    unsigned xcd;
    asm("s_getreg_b32 %0, hwreg(HW_REG_XCC_ID)" : "=s"(xcd));
    xcd &= 7;
    int* cb = cnt8 + xcd * NN;
    unsigned short* pb = colp8 + (size_t)xcd * NN * RCAP;
    const int e4 = (bid * 256 + threadIdx.x) * 4;
    if (e4 + 3 < EE) {
      const int4 d4 = *(const int4*)(dst + e4);
      const int4 s4 = *(const int4*)(src + e4);
      const int p0 = __hip_atomic_fetch_add(&cb[d4.x], 1, __ATOMIC_RELAXED,
                                            __HIP_MEMORY_SCOPE_WORKGROUP);
      const int p1 = __hip_atomic_fetch_add(&cb[d4.y], 1, __ATOMIC_RELAXED,
                                            __HIP_MEMORY_SCOPE_WORKGROUP);
      const int p2 = __hip_atomic_fetch_add(&cb[d4.z], 1, __ATOMIC_RELAXED,
                                            __HIP_MEMORY_SCOPE_WORKGROUP);
      const int p3 = __hip_atomic_fetch_add(&cb[d4.w], 1, __ATOMIC_RELAXED,
                                            __HIP_MEMORY_SCOPE_WORKGROUP);
      if (p0 < RCAP) pb[d4.x * RCAP + p0] = (unsigned short)s4.x;
      if (p1 < RCAP) pb[d4.y * RCAP + p1] = (unsigned short)s4.y;
      if (p2 < RCAP) pb[d4.z * RCAP + p2] = (unsigned short)s4.z;
      if (p3 < RCAP) pb[d4.w * RCAP + p3] = (unsigned short)s4.w;
    } else {
      for (int j = 0; j < 4; ++j) {
        const int e = e4 + j;
        if (e < EE) {
          const int d = dst[e];
          const int sv = src[e];
          const int pos = __hip_atomic_fetch_add(&cb[d], 1, __ATOMIC_RELAXED,
                                                 __HIP_MEMORY_SCOPE_WORKGROUP);
          if (pos < RCAP) pb[d * RCAP + pos] = (unsigned short)sv;
        }
      }
    }
    return;
  }
  if (bid < SCATB + WPB) {
    // ---- wpack role: W[k][c] = sum_ff fc_w[kk][hh*64+ff]*out_w[hh*64+ff][c]
    const int idx = (bid - SCATB) * 256 + threadIdx.x;   // < WPACK_N
    const int j = idx & 7;
    const int l = (idx >> 3) & 63;
    const int t = (idx >> 9) & 7;
    const int ct = idx >> 12;
    const int k = 32 * t + (l >> 4) * 8 + j;        // 0..255 (= hh*64+kk)
    const int c = 16 * ct + (l & 15);               // 0..63
    const int hh = k >> 6, kk = k & 63;
    const float* fw = fc_w + kk * HF + hh * FF;
    const float* ow = out_w + (size_t)(hh * FF) * FF + c;
    float acc = 0.f;
#pragma unroll
    for (int ff = 0; ff < FF; ++ff) acc = fmaf(fw[ff], ow[(size_t)ff * FF], acc);
    wpack[idx] = f32_to_bf16_rne(acc);
    return;
  }
  // ---- elr role: hb = bf16(h); el/er = h @ alv/arv (R8 8-lane layout) ----
  const int wave = threadIdx.x >> 6;
  const int lane = threadIdx.x & 63;
  const int row = (bid - SCATB - WPB) * 32 + wave * 8 + (lane >> 3);
  if (row >= NN) return;                            // wave-uniform (NN%8==0)
  const int kc = (lane & 7) * 8;

  float hv[8];
  *(float4*)hv = *(const float4*)(h + (size_t)row * FF + kc);
  *(float4*)(hv + 4) = *(const float4*)(h + (size_t)row * FF + kc + 4);

  unsigned pk[4];
#pragma unroll
  for (int jj = 0; jj < 4; ++jj)
    pk[jj] = (unsigned)f32_to_bf16_rne(hv[2 * jj]) |
             ((unsigned)f32_to_bf16_rne(hv[2 * jj + 1]) << 16);
  *(uint4*)(hb + (size_t)row * FF + kc) = make_uint4(pk[0], pk[1], pk[2], pk[3]);

  float p[8];
#pragma unroll
  for (int hh = 0; hh < 4; ++hh) {
    const float* av = alv + (hh << 6) + kc;
    const float* bv = arv + (hh << 6) + kc;
    float sa = 0.f, sb = 0.f;
#pragma unroll
    for (int j = 0; j < 8; ++j) {
      sa = fmaf(hv[j], av[j], sa);
      sb = fmaf(hv[j], bv[j], sb);
    }
    p[hh] = sa; p[4 + hh] = sb;
  }
#pragma unroll
  for (int off = 1; off < 8; off <<= 1) {
#pragma unroll
    for (int q = 0; q < 8; ++q) p[q] += __shfl_xor(p[q], off, 64);
  }
  const int q = lane & 7;
  if (q < 4) el[(size_t)row * 4 + q] = p[q];
  else       er[(size_t)row * 4 + (q - 4)] = p[q];
}

// ------- Fused Kernel: MFMA-gather + folded out-GEMM + LayerNorm -----------
// Byte-identical to R11 (proven 51us): MFMA per-node tiny GEMM, parallel
// segment select, 4-wave epilogue. (R11 note: the granule swizzle is
// bank-neutral -- kept only to avoid churn; 1.4M conflict cycles = 0.004%
// of CU-cycles, not a cost.)
__global__ __launch_bounds__(256) void k_gather_out(
    const unsigned short* __restrict__ hb, const float* __restrict__ el,
    const float* __restrict__ er, const int* __restrict__ cnt8,
    const unsigned short* __restrict__ colp8,
    const unsigned short* __restrict__ wpack, const float* __restrict__ outb2,
    const float* __restrict__ ln_g, const float* __restrict__ ln_b,
    float* __restrict__ out) {
  __shared__ unsigned short tile[16][TROW];  // 8.25 KB, rows padded +16B
  __shared__ float part[4][16][2];           // 512 B LN partials
  __shared__ unsigned short xa[4][2560];     // per wave: X[2048] + A[512]
  const int wave = threadIdx.x >> 6;
  const int lane = threadIdx.x & 63;
  const int n0 = blockIdx.x * 16;
  const int nbase = n0 + wave * 4;
  unsigned short* Xw = &xa[wave][0];         // [4][64][8] bf16, swizzled
  unsigned short* Aw = &xa[wave][2048];      // [4][16][8] bf16

  // ---- parallel count load + prefix (lanes 0..31: seg = lane>>2, node = lane&3)
  int cgrp = 0;
  if (lane < 32) cgrp = cnt8[(lane >> 2) * NN + nbase + (lane & 3)];
  cgrp = cgrp > RCAP ? RCAP : cgrp;
  int inc = cgrp;
#pragma unroll
  for (int off = 4; off <= 16; off <<= 1) {
    const int t = __shfl_up(inc, off, 64);
    if (lane >= off) inc += t;
  }
  const int exc = inc - cgrp;                // exclusive prefix per (seg,node)

#pragma unroll
  for (int r = 0; r < 4; ++r) {
    const int row = wave * 4 + r;
    const int n = nbase + r;
    const float4 erv = *(const float4*)(er + (size_t)n * 4);

    const int mi = __builtin_amdgcn_readlane(inc, 28 + r);
    const int m = mi > 64 ? 64 : mi;
    const int p1 = __builtin_amdgcn_readlane(exc, 4 + r);
    const int p2 = __builtin_amdgcn_readlane(exc, 8 + r);
    const int p3 = __builtin_amdgcn_readlane(exc, 12 + r);
    const int p4 = __builtin_amdgcn_readlane(exc, 16 + r);
    const int p5 = __builtin_amdgcn_readlane(exc, 20 + r);
    const int p6 = __builtin_amdgcn_readlane(exc, 24 + r);
    const int p7 = __builtin_amdgcn_readlane(exc, 28 + r);
    // monotone p1<=...<=p7: seg = #{p_x <= lane}, pb = exc[seg]
    int seg = 0, pb = 0;
    if (lane >= p1) { seg = 1; pb = p1; }
    if (lane >= p2) { seg = 2; pb = p2; }
    if (lane >= p3) { seg = 3; pb = p3; }
    if (lane >= p4) { seg = 4; pb = p4; }
    if (lane >= p5) { seg = 5; pb = p5; }
    if (lane >= p6) { seg = 6; pb = p6; }
    if (lane >= p7) { seg = 7; pb = p7; }
    int s = 0;
    if (lane < m)
      s = colp8[((size_t)seg * NN + n) * RCAP + (lane - pb)];

    float w0 = 0.f, w1 = 0.f, w2 = 0.f, w3 = 0.f;
    if (lane < m) {
      const float4 elv = *(const float4*)(el + (size_t)s * 4);
      float e0 = elv.x + erv.x, e1 = elv.y + erv.y;
      float e2 = elv.z + erv.z, e3 = elv.w + erv.w;
      e0 = e0 > 0.f ? e0 : NEG_SLOPE * e0;
      e1 = e1 > 0.f ? e1 : NEG_SLOPE * e1;
      e2 = e2 > 0.f ? e2 : NEG_SLOPE * e2;
      e3 = e3 > 0.f ? e3 : NEG_SLOPE * e3;
      w0 = __expf(e0); w1 = __expf(e1);
      w2 = __expf(e2); w3 = __expf(e3);
    }
    // softmax denominator once per node (lanes >= m hold w = 0)
    float z0 = w0, z1 = w1, z2 = w2, z3 = w3;
#pragma unroll
    for (int off = 1; off < 64; off <<= 1) {
      z0 += __shfl_xor(z0, off, 64);
      z1 += __shfl_xor(z1, off, 64);
      z2 += __shfl_xor(z2, off, 64);
      z3 += __shfl_xor(z3, off, 64);
    }
    w0 *= (z0 > 0.f ? 1.f / z0 : 0.f);
    w1 *= (z1 > 0.f ? 1.f / z1 : 0.f);
    w2 *= (z2 > 0.f ? 1.f / z2 : 0.f);
    w3 *= (z3 > 0.f ? 1.f / z3 : 0.f);

    // ---- A-tile: normalized weights (bf16) at rows h*4, cols = slot ----
    if (lane < 32) {
      const int ai = ((lane >> 3) << 7) | (lane & 7);
      Aw[ai]      = f32_to_bf16_rne(w0);
      Aw[ai + 32] = f32_to_bf16_rne(w1);
      Aw[ai + 64] = f32_to_bf16_rne(w2);
      Aw[ai + 96] = f32_to_bf16_rne(w3);
    }

    // ---- X-tile: gather 32 slots (uniform; pad lanes re-read row 0) ----
#pragma unroll
    for (int e = 0; e < 32; e += 8) {
      unsigned short t0, t1, t2, t3, t4, t5, t6, t7;
      t0 = hb[((unsigned)__builtin_amdgcn_readlane(s, e + 0) << 6) + lane];
      t1 = hb[((unsigned)__builtin_amdgcn_readlane(s, e + 1) << 6) + lane];
      t2 = hb[((unsigned)__builtin_amdgcn_readlane(s, e + 2) << 6) + lane];
      t3 = hb[((unsigned)__builtin_amdgcn_readlane(s, e + 3) << 6) + lane];
      t4 = hb[((unsigned)__builtin_amdgcn_readlane(s, e + 4) << 6) + lane];
      t5 = hb[((unsigned)__builtin_amdgcn_readlane(s, e + 5) << 6) + lane];
      t6 = hb[((unsigned)__builtin_amdgcn_readlane(s, e + 6) << 6) + lane];
      t7 = hb[((unsigned)__builtin_amdgcn_readlane(s, e + 7) << 6) + lane];
      const unsigned u0 = (unsigned)t0 | ((unsigned)t1 << 16);
      const unsigned u1 = (unsigned)t2 | ((unsigned)t3 << 16);
      const unsigned u2 = (unsigned)t4 | ((unsigned)t5 << 16);
      const unsigned u3 = (unsigned)t6 | ((unsigned)t7 << 16);
      // swizzled granule: row = e + (lane>>3); g = (l&7)^(row&7)^(row>>3)
      const int gsw = (lane & 7) ^ (lane >> 3) ^ (e >> 3);
      *(uint4*)(Xw + ((e + (lane >> 3)) << 6) + (gsw << 3)) =
          make_uint4(u0, u1, u2, u3);
    }

    // ---- 4 MFMAs: g[head][feat]; A-frag row=l&15, k=(l>>4)*8+j ----
    const s8v af = *(const s8v*)(Aw + (((lane >> 4) << 7) | ((lane & 15) << 3)));
    f4v acc[4];
#pragma unroll
    for (int ct = 0; ct < 4; ++ct) {
      const f4v z4 = {0.f, 0.f, 0.f, 0.f};
      const int f = lane & 15;
      const int rowr = ((lane >> 4) << 3) + (ct << 1) + (f >> 3);
      const int gsr = (f & 7) ^ ((ct << 1) + (f >> 3)) ^ (lane >> 4);
      const s8v bf = *(const s8v*)(Xw + (rowr << 6) + (gsr << 3));
      acc[ct] = __builtin_amdgcn_mfma_f32_16x16x32_bf16(af, bf, z4, 0, 0, 0);
    }

    if (m > 32) {                              // rare: slots 32..63
      if (lane >= 32) {
        const int e2 = lane - 32;
        const int ai = ((e2 >> 3) << 7) | (e2 & 7);
        Aw[ai]      = f32_to_bf16_rne(w0);
        Aw[ai + 32] = f32_to_bf16_rne(w1);
        Aw[ai + 64] = f32_to_bf16_rne(w2);
        Aw[ai + 96] = f32_to_bf16_rne(w3);
      }
#pragma unroll
      for (int e = 32; e < 64; e += 8) {
        unsigned short t0, t1, t2, t3, t4, t5, t6, t7;
        t0 = hb[((unsigned)__builtin_amdgcn_readlane(s, e + 0) << 6) + lane];
        t1 = hb[((unsigned)__builtin_amdgcn_readlane(s, e + 1) << 6) + lane];
        t2 = hb[((unsigned)__builtin_amdgcn_readlane(s, e + 2) << 6) + lane];
        t3 = hb[((unsigned)__builtin_amdgcn_readlane(s, e + 3) << 6) + lane];
        t4 = hb[((unsigned)__builtin_amdgcn_readlane(s, e + 4) << 6) + lane];
        t5 = hb[((unsigned)__builtin_amdgcn_readlane(s, e + 5) << 6) + lane];
        t6 = hb[((unsigned)__builtin_amdgcn_readlane(s, e + 6) << 6) + lane];
        t7 = hb[((unsigned)__builtin_amdgcn_readlane(s, e + 7) << 6) + lane];
        const unsigned u0 = (unsigned)t0 | ((unsigned)t1 << 16);
        const unsigned u1 = (unsigned)t2 | ((unsigned)t3 << 16);
        const unsigned u2 = (unsigned)t4 | ((unsigned)t5 << 16);
        const unsigned u3 = (unsigned)t6 | ((unsigned)t7 << 16);
        const int eb = e - 32;
        const int gsw = (lane & 7) ^ (lane >> 3) ^ (eb >> 3);
        *(uint4*)(Xw + ((eb + (lane >> 3)) << 6) + (gsw << 3)) =
            make_uint4(u0, u1, u2, u3);
      }
      const s8v af2 = *(const s8v*)(Aw + (((lane >> 4) << 7) | ((lane & 15) << 3)));
#pragma unroll
      for (int ct = 0; ct < 4; ++ct) {
        const int f = lane & 15;
        const int rowr = ((lane >> 4) << 3) + (ct << 1) + (f >> 3);
        const int gsr = (f & 7) ^ ((ct << 1) + (f >> 3)) ^ (lane >> 4);
        const s8v bf = *(const s8v*)(Xw + (rowr << 6) + (gsr << 3));
        acc[ct] = __builtin_amdgcn_mfma_f32_16x16x32_bf16(af2, bf, acc[ct], 0, 0, 0);
      }
    }

    // ---- g row -> tile: C row h*4 = reg 0 of quad h ----
    const int q = lane >> 4, r2 = lane & 15;
#pragma unroll
    for (int ct = 0; ct < 4; ++ct)
      tile[row][(q << 6) | (ct << 4) | r2] = f32_to_bf16_rne(acc[ct][0]);
  }
  __syncthreads();

  // ---- out-GEMM: wave w computes column-tile ct = w (8 MFMAs each) ----
  const int cl = lane & 15;
  const int quad = lane >> 4;
  s8v a[8];
#pragma unroll
  for (int t = 0; t < 8; ++t)
    a[t] = *(const s8v*)(&tile[cl][32 * t + quad * 8]);

  f4v acc = {0.f, 0.f, 0.f, 0.f};
#pragma unroll
  for (int t = 0; t < 8; ++t) {
    const s8v b = *(const s8v*)(wpack + ((wave * 8 + t) * 64 + lane) * 8);
    acc = __builtin_amdgcn_mfma_f32_16x16x32_bf16(a[t], b, acc, 0, 0, 0);
  }

  const float ob = outb2[16 * wave + cl];
  float xv[4];
#pragma unroll
  for (int r = 0; r < 4; ++r) {
    const float v = acc[r] + ob;
    xv[r] = v;
    float p1 = v, p2 = v * v;
#pragma unroll
    for (int off = 1; off < 16; off <<= 1) {
      p1 += __shfl_xor(p1, off, 64);
      p2 += __shfl_xor(p2, off, 64);
    }
    if (cl == 0) {
      part[wave][quad * 4 + r][0] = p1;
      part[wave][quad * 4 + r][1] = p2;
    }
  }
  __syncthreads();
#pragma unroll
  for (int r = 0; r < 4; ++r) {
    const int row = quad * 4 + r;
    const float t1 = part[0][row][0] + part[1][row][0] +
                     part[2][row][0] + part[3][row][0];
    const float t2 = part[0][row][1] + part[1][row][1] +
                     part[2][row][1] + part[3][row][1];
    const float mu = t1 * (1.f / 64.f);
    const float var = t2 * (1.f / 64.f) - mu * mu;
    const float inv = rsqrtf(var + LN_EPS);
    const int c = 16 * wave + cl;
    out[(size_t)(n0 + row) * FF + c] = (xv[r] - mu) * inv * ln_g[c] + ln_b[c];
  }
}

// ---------------- launch ---------------------------------------------------
extern "C" void kernel_launch(void* const* d_in, const int* in_sizes, int n_in,
                              void* d_out, int out_size, void* d_ws,
                              size_t ws_size, hipStream_t stream) {
  const float* h_in   = (const float*)d_in[0];
  const int*   src    = (const int*)d_in[1];
  const int*   dst    = (const int*)d_in[2];
  const float* fc_w   = (const float*)d_in[3];
  const float* attn_l = (const float*)d_in[4];
  const float* attn_r = (const float*)d_in[5];
  const float* gbias  = (const float*)d_in[6];
  const float* out_w  = (const float*)d_in[7];
  const float* out_b  = (const float*)d_in[8];
  const float* ln_g   = (const float*)d_in[9];
  const float* ln_b   = (const float*)d_in[10];
  float* out = (float*)d_out;

  char* p = (char*)d_ws;
  auto alloc = [&](size_t bytes) {
    char* q = p;
    p += (bytes + 255) & ~(size_t)255;
    return q;
  };
  unsigned short* hb     = (unsigned short*)alloc((size_t)NN * FF * 2); // 6.4 MB
  unsigned short* wpack  = (unsigned short*)alloc((size_t)WPACK_N * 2);
  float* alv     = (float*)alloc(256 * 4);
  float* arv     = (float*)alloc(256 * 4);
  float* outb2   = (float*)alloc(64 * 4);
  float* el      = (float*)alloc((size_t)NN * HH * 4);
  float* er      = (float*)alloc((size_t)NN * HH * 4);
  int*   cnt8    = (int*)alloc((size_t)NXCD * NN * 4);                  // 1.6 MB
  unsigned short* colp8 =
      (unsigned short*)alloc((size_t)NXCD * NN * RCAP * 2);             // 25.6 MB

  hipMemsetAsync(cnt8, 0, (size_t)NXCD * NN * 4, stream);
  k_small<<<3, 256, 0, stream>>>(fc_w, attn_l, attn_r, gbias, out_w, out_b,
                                 alv, arv, outb2);
  k_fused<<<SCATB + WPB + ELRB, 256, 0, stream>>>(
      src, dst, cnt8, colp8, fc_w, out_w, wpack, h_in, alv, arv, hb, el, er);
  k_gather_out<<<NTILE, 256, 0, stream>>>(hb, el, er, cnt8, colp8, wpack,
                                          outb2, ln_g, ln_b, out);
}

// Round 13
// 174.827 us; speedup vs baseline: 1.1115x; 1.1115x over previous
//
#include <hip/hip_runtime.h>

#define NN 50000
#define EE 800000
#define FF 64
#define HH 4
#define HF 256          // H*F
#define NEG_SLOPE 0.2f
#define LN_EPS 1e-5f
#define WPACK_N (4 * 8 * 64 * 8)   // 16384 bf16 elements (W B-frags)
#define NTILE (NN / 16)            // 3125 node tiles
#define TROW 264                   // LDS tile row stride (256 + 8 pad)
#define NXCD 8
#define RCAP 32                    // per-XCD replica row = exactly one 64B line

typedef __attribute__((ext_vector_type(8))) short s8v;    // 8 bf16 (4 VGPRs)
typedef __attribute__((ext_vector_type(4))) float f4v;    // 4 fp32 acc

__device__ __forceinline__ unsigned short f32_to_bf16_rne(float x) {
  unsigned int u = __float_as_uint(x);
  unsigned int r = u + 0x7FFFu + ((u >> 16) & 1u);
  return (unsigned short)(r >> 16);
}

// ---------------- Kernel P: fold weights + zero cnt8 (R10 form) ------------
// Algebraic restructure (R6, proven): rst_flat @ out_w == sum_h g_h @ W_h,
// el/er = h @ alv/arv, gat_bias folded into outb2. feat never materialized.
// (R12's memset+k_small+fused split regressed; this fused prep is the
// proven-best form.)
__global__ __launch_bounds__(256) void k_prep(
    const float* __restrict__ fc_w, const float* __restrict__ out_w,
    const float* __restrict__ attn_l, const float* __restrict__ attn_r,
    const float* __restrict__ gat_bias, const float* __restrict__ out_b,
    unsigned short* __restrict__ wpack, float* __restrict__ alv,
    float* __restrict__ arv, float* __restrict__ outb2,
    int* __restrict__ cnt8) {
  const int idx = blockIdx.x * 256 + threadIdx.x;   // < 400128
  if (idx < WPACK_N) {
    const int j = idx & 7;
    const int l = (idx >> 3) & 63;
    const int t = (idx >> 9) & 7;
    const int ct = idx >> 12;
    const int k = 32 * t + (l >> 4) * 8 + j;        // 0..255 (= hh*64+kk)
    const int c = 16 * ct + (l & 15);               // 0..63
    const int hh = k >> 6, kk = k & 63;
    const float* fw = fc_w + kk * HF + hh * FF;
    const float* ow = out_w + (size_t)(hh * FF) * FF + c;
    float acc = 0.f;
#pragma unroll
    for (int ff = 0; ff < FF; ++ff) acc = fmaf(fw[ff], ow[(size_t)ff * FF], acc);
    wpack[idx] = f32_to_bf16_rne(acc);
  } else if (idx < WPACK_N + 512) {
    const int i = idx - WPACK_N;                    // 0..511
    const int hh = (i >> 6) & 3, kk = i & 63;
    const float* fw = fc_w + kk * HF + hh * FF;
    const float* at = (i < 256 ? attn_l : attn_r) + hh * FF;
    float acc = 0.f;
#pragma unroll
    for (int ff = 0; ff < FF; ++ff) acc = fmaf(fw[ff], at[ff], acc);
    (i < 256 ? alv : arv)[(hh << 6) | kk] = acc;
  } else if (idx < WPACK_N + 512 + FF) {
    const int c = idx - WPACK_N - 512;              // 0..63
    float acc = out_b[c];
    for (int k = 0; k < HF; ++k) acc = fmaf(gat_bias[k], out_w[(size_t)k * FF + c], acc);
    outb2[c] = acc;
  }
  if (idx < NXCD * NN) cnt8[idx] = 0;   // graph-safe: re-zeroed every launch
}

// ---------------- Kernel E: hb = bf16(h) ; el/er = h @ alv/arv -------------
// 8-lane-per-row layout (R8, proven): lane owns an 8-float chunk; 64 FMA per
// lane; 3-step x 8-value butterfly. All loads/stores coalesced; hb fused.
__global__ __launch_bounds__(256) void k_elr(
    const float* __restrict__ h, const float* __restrict__ alv,
    const float* __restrict__ arv, unsigned short* __restrict__ hb,
    float* __restrict__ el, float* __restrict__ er) {
  const int wave = threadIdx.x >> 6;
  const int lane = threadIdx.x & 63;
  const int row = blockIdx.x * 32 + wave * 8 + (lane >> 3);
  if (row >= NN) return;                            // wave-uniform (NN%8==0)
  const int kc = (lane & 7) * 8;

  float hv[8];
  *(float4*)hv = *(const float4*)(h + (size_t)row * FF + kc);
  *(float4*)(hv + 4) = *(const float4*)(h + (size_t)row * FF + kc + 4);

  unsigned pk[4];
#pragma unroll
  for (int jj = 0; jj < 4; ++jj)
    pk[jj] = (unsigned)f32_to_bf16_rne(hv[2 * jj]) |
             ((unsigned)f32_to_bf16_rne(hv[2 * jj + 1]) << 16);
  *(uint4*)(hb + (size_t)row * FF + kc) = make_uint4(pk[0], pk[1], pk[2], pk[3]);

  float p[8];
#pragma unroll
  for (int hh = 0; hh < 4; ++hh) {
    const float* av = alv + (hh << 6) + kc;
    const float* bv = arv + (hh << 6) + kc;
    float sa = 0.f, sb = 0.f;
#pragma unroll
    for (int j = 0; j < 8; ++j) {
      sa = fmaf(hv[j], av[j], sa);
      sb = fmaf(hv[j], bv[j], sb);
    }
    p[hh] = sa; p[4 + hh] = sb;
  }
#pragma unroll
  for (int off = 1; off < 8; off <<= 1) {
#pragma unroll
    for (int q = 0; q < 8; ++q) p[q] += __shfl_xor(p[q], off, 64);
  }
  const int q = lane & 7;
  if (q < 4) el[(size_t)row * 4 + q] = p[q];
  else       er[(size_t)row * 4 + (q - 4)] = p[q];
}

// ---------------- XCD-local padded-CSR build (R10 form, RCAP 32) -----------
// 1 edge/thread, 3125 blocks: R11's ILP4 was null (it conserved total
// in-flight atomics: 16 waves/CU x MLP1 == 6 waves/CU x MLP4). The wall is
// per-request processing of 2 scattered ops/edge (~40 cy/pair/CU == 52us),
// structural across all tried variants. Workgroup-scope atomics complete in
// the local TCC; 8 disjoint replicas need no cross-XCD coherence.
__global__ void k_scatter(
    const int* __restrict__ src, const int* __restrict__ dst,
    int* __restrict__ cnt8, unsigned short* __restrict__ colp8) {
  unsigned xcd;
  asm("s_getreg_b32 %0, hwreg(HW_REG_XCC_ID)" : "=s"(xcd));
  xcd &= 7;                                       // safety clamp
  const int e = blockIdx.x * 256 + threadIdx.x;
  if (e < EE) {
    const int d = dst[e];
    const int sv = src[e];
    const int pos = __hip_atomic_fetch_add(&cnt8[xcd * NN + d], 1,
                                           __ATOMIC_RELAXED,
                                           __HIP_MEMORY_SCOPE_WORKGROUP);
    if (pos < RCAP)
      colp8[((size_t)xcd * NN + d) * RCAP + pos] = (unsigned short)sv;
  }
}

// ------- Fused Kernel: MFMA-gather + folded out-GEMM + LayerNorm -----------
// R11 gather (proven ~51us) with ONE change: the softmax denominator z is
// computed by the MATRIX pipe instead of the 6-step x 4-value shuffle
// butterfly (~24 dependent cross-lane ops, ~30cy each -- the longest serial
// chain per node). A-tile holds RAW bf16 w; one extra mfma(af, ones, 0)
// yields z_h = sum_k w (B = all-ones splat; D[4h][c] = z_h, every column).
// Normalization moves after the MFMAs: g * (1/z), 1 rcp + 4 mul/lane, with
// the z>0 guard preserving empty-node semantics. z now sums exactly the
// same bf16 w values that weight the numerator.
__global__ __launch_bounds__(256) void k_gather_out(
    const unsigned short* __restrict__ hb, const float* __restrict__ el,
    const float* __restrict__ er, const int* __restrict__ cnt8,
    const unsigned short* __restrict__ colp8,
    const unsigned short* __restrict__ wpack, const float* __restrict__ outb2,
    const float* __restrict__ ln_g, const float* __restrict__ ln_b,
    float* __restrict__ out) {
  __shared__ unsigned short tile[16][TROW];  // 8.25 KB, rows padded +16B
  __shared__ float part[4][16][2];           // 512 B LN partials
  __shared__ unsigned short xa[4][2560];     // per wave: X[2048] + A[512]
  const int wave = threadIdx.x >> 6;
  const int lane = threadIdx.x & 63;
  const int n0 = blockIdx.x * 16;
  const int nbase = n0 + wave * 4;
  unsigned short* Xw = &xa[wave][0];         // [4][64][8] bf16, swizzled
  unsigned short* Aw = &xa[wave][2048];      // [4][16][8] bf16

  s8v bz;                                    // B = all-ones (bf16 1.0)
#pragma unroll
  for (int j = 0; j < 8; ++j) bz[j] = (short)0x3F80;

  // ---- parallel count load + prefix (lanes 0..31: seg = lane>>2, node = lane&3)
  int cgrp = 0;
  if (lane < 32) cgrp = cnt8[(lane >> 2) * NN + nbase + (lane & 3)];
  cgrp = cgrp > RCAP ? RCAP : cgrp;
  int inc = cgrp;
#pragma unroll
  for (int off = 4; off <= 16; off <<= 1) {
    const int t = __shfl_up(inc, off, 64);
    if (lane >= off) inc += t;
  }
  const int exc = inc - cgrp;                // exclusive prefix per (seg,node)

#pragma unroll
  for (int r = 0; r < 4; ++r) {
    const int row = wave * 4 + r;
    const int n = nbase + r;
    const float4 erv = *(const float4*)(er + (size_t)n * 4);

    const int mi = __builtin_amdgcn_readlane(inc, 28 + r);
    const int m = mi > 64 ? 64 : mi;
    const int p1 = __builtin_amdgcn_readlane(exc, 4 + r);
    const int p2 = __builtin_amdgcn_readlane(exc, 8 + r);
    const int p3 = __builtin_amdgcn_readlane(exc, 12 + r);
    const int p4 = __builtin_amdgcn_readlane(exc, 16 + r);
    const int p5 = __builtin_amdgcn_readlane(exc, 20 + r);
    const int p6 = __builtin_amdgcn_readlane(exc, 24 + r);
    const int p7 = __builtin_amdgcn_readlane(exc, 28 + r);
    // monotone p1<=...<=p7: seg = #{p_x <= lane}, pb = exc[seg]
    int seg = 0, pb = 0;
    if (lane >= p1) { seg = 1; pb = p1; }
    if (lane >= p2) { seg = 2; pb = p2; }
    if (lane >= p3) { seg = 3; pb = p3; }
    if (lane >= p4) { seg = 4; pb = p4; }
    if (lane >= p5) { seg = 5; pb = p5; }
    if (lane >= p6) { seg = 6; pb = p6; }
    if (lane >= p7) { seg = 7; pb = p7; }
    int s = 0;
    if (lane < m)
      s = colp8[((size_t)seg * NN + n) * RCAP + (lane - pb)];

    float w0 = 0.f, w1 = 0.f, w2 = 0.f, w3 = 0.f;
    if (lane < m) {
      const float4 elv = *(const float4*)(el + (size_t)s * 4);
      float e0 = elv.x + erv.x, e1 = elv.y + erv.y;
      float e2 = elv.z + erv.z, e3 = elv.w + erv.w;
      e0 = e0 > 0.f ? e0 : NEG_SLOPE * e0;
      e1 = e1 > 0.f ? e1 : NEG_SLOPE * e1;
      e2 = e2 > 0.f ? e2 : NEG_SLOPE * e2;
      e3 = e3 > 0.f ? e3 : NEG_SLOPE * e3;
      w0 = __expf(e0); w1 = __expf(e1);
      w2 = __expf(e2); w3 = __expf(e3);
    }

    // ---- A-tile: RAW bf16 weights at rows h*4, cols = slot ----
    if (lane < 32) {
      const int ai = ((lane >> 3) << 7) | (lane & 7);
      Aw[ai]      = f32_to_bf16_rne(w0);
      Aw[ai + 32] = f32_to_bf16_rne(w1);
      Aw[ai + 64] = f32_to_bf16_rne(w2);
      Aw[ai + 96] = f32_to_bf16_rne(w3);
    }

    // ---- X-tile: gather 32 slots (uniform; pad lanes re-read row 0) ----
#pragma unroll
    for (int e = 0; e < 32; e += 8) {
      unsigned short t0, t1, t2, t3, t4, t5, t6, t7;
      t0 = hb[((unsigned)__builtin_amdgcn_readlane(s, e + 0) << 6) + lane];
      t1 = hb[((unsigned)__builtin_amdgcn_readlane(s, e + 1) << 6) + lane];
      t2 = hb[((unsigned)__builtin_amdgcn_readlane(s, e + 2) << 6) + lane];
      t3 = hb[((unsigned)__builtin_amdgcn_readlane(s, e + 3) << 6) + lane];
      t4 = hb[((unsigned)__builtin_amdgcn_readlane(s, e + 4) << 6) + lane];
      t5 = hb[((unsigned)__builtin_amdgcn_readlane(s, e + 5) << 6) + lane];
      t6 = hb[((unsigned)__builtin_amdgcn_readlane(s, e + 6) << 6) + lane];
      t7 = hb[((unsigned)__builtin_amdgcn_readlane(s, e + 7) << 6) + lane];
      const unsigned u0 = (unsigned)t0 | ((unsigned)t1 << 16);
      const unsigned u1 = (unsigned)t2 | ((unsigned)t3 << 16);
      const unsigned u2 = (unsigned)t4 | ((unsigned)t5 << 16);
      const unsigned u3 = (unsigned)t6 | ((unsigned)t7 << 16);
      const int gsw = (lane & 7) ^ (lane >> 3) ^ (e >> 3);
      *(uint4*)(Xw + ((e + (lane >> 3)) << 6) + (gsw << 3)) =
          make_uint4(u0, u1, u2, u3);
    }

    // ---- 5 MFMAs: g[head][feat] + z[head]; A row=l&15, k=(l>>4)*8+j ----
    const s8v af = *(const s8v*)(Aw + (((lane >> 4) << 7) | ((lane & 15) << 3)));
    const f4v z4 = {0.f, 0.f, 0.f, 0.f};
    f4v acc_z = __builtin_amdgcn_mfma_f32_16x16x32_bf16(af, bz, z4, 0, 0, 0);
    f4v acc[4];
#pragma unroll
    for (int ct = 0; ct < 4; ++ct) {
      const int f = lane & 15;
      const int rowr = ((lane >> 4) << 3) + (ct << 1) + (f >> 3);
      const int gsr = (f & 7) ^ ((ct << 1) + (f >> 3)) ^ (lane >> 4);
      const s8v bf = *(const s8v*)(Xw + (rowr << 6) + (gsr << 3));
      acc[ct] = __builtin_amdgcn_mfma_f32_16x16x32_bf16(af, bf, z4, 0, 0, 0);
    }

    if (m > 32) {                              // rare: slots 32..63
      if (lane >= 32) {
        const int e2 = lane - 32;
        const int ai = ((e2 >> 3) << 7) | (e2 & 7);
        Aw[ai]      = f32_to_bf16_rne(w0);
        Aw[ai + 32] = f32_to_bf16_rne(w1);
        Aw[ai + 64] = f32_to_bf16_rne(w2);
        Aw[ai + 96] = f32_to_bf16_rne(w3);
      }
#pragma unroll
      for (int e = 32; e < 64; e += 8) {
        unsigned short t0, t1, t2, t3, t4, t5, t6, t7;
        t0 = hb[((unsigned)__builtin_amdgcn_readlane(s, e + 0) << 6) + lane];
        t1 = hb[((unsigned)__builtin_amdgcn_readlane(s, e + 1) << 6) + lane];
        t2 = hb[((unsigned)__builtin_amdgcn_readlane(s, e + 2) << 6) + lane];
        t3 = hb[((unsigned)__builtin_amdgcn_readlane(s, e + 3) << 6) + lane];
        t4 = hb[((unsigned)__builtin_amdgcn_readlane(s, e + 4) << 6) + lane];
        t5 = hb[((unsigned)__builtin_amdgcn_readlane(s, e + 5) << 6) + lane];
        t6 = hb[((unsigned)__builtin_amdgcn_readlane(s, e + 6) << 6) + lane];
        t7 = hb[((unsigned)__builtin_amdgcn_readlane(s, e + 7) << 6) + lane];
        const unsigned u0 = (unsigned)t0 | ((unsigned)t1 << 16);
        const unsigned u1 = (unsigned)t2 | ((unsigned)t3 << 16);
        const unsigned u2 = (unsigned)t4 | ((unsigned)t5 << 16);
        const unsigned u3 = (unsigned)t6 | ((unsigned)t7 << 16);
        const int eb = e - 32;
        const int gsw = (lane & 7) ^ (lane >> 3) ^ (eb >> 3);
        *(uint4*)(Xw + ((eb + (lane >> 3)) << 6) + (gsw << 3)) =
            make_uint4(u0, u1, u2, u3);
      }
      const s8v af2 = *(const s8v*)(Aw + (((lane >> 4) << 7) | ((lane & 15) << 3)));
      acc_z = __builtin_amdgcn_mfma_f32_16x16x32_bf16(af2, bz, acc_z, 0, 0, 0);
#pragma unroll
      for (int ct = 0; ct < 4; ++ct) {
        const int f = lane & 15;
        const int rowr = ((lane >> 4) << 3) + (ct << 1) + (f >> 3);
        const int gsr = (f & 7) ^ ((ct << 1) + (f >> 3)) ^ (lane >> 4);
        const s8v bf = *(const s8v*)(Xw + (rowr << 6) + (gsr << 3));
        acc[ct] = __builtin_amdgcn_mfma_f32_16x16x32_bf16(af2, bf, acc[ct], 0, 0, 0);
      }
    }

    // ---- normalize + g row -> tile: C row h*4 = reg 0 of quad h ----
    const float zq = acc_z[0];
    const float zi = zq > 0.f ? 1.f / zq : 0.f;
    const int q = lane >> 4, r2 = lane & 15;
#pragma unroll
    for (int ct = 0; ct < 4; ++ct)
      tile[row][(q << 6) | (ct << 4) | r2] = f32_to_bf16_rne(acc[ct][0] * zi);
  }
  __syncthreads();

  // ---- out-GEMM: wave w computes column-tile ct = w (8 MFMAs each) ----
  const int cl = lane & 15;
  const int quad = lane >> 4;
  s8v a[8];
#pragma unroll
  for (int t = 0; t < 8; ++t)
    a[t] = *(const s8v*)(&tile[cl][32 * t + quad * 8]);

  f4v acc = {0.f, 0.f, 0.f, 0.f};
#pragma unroll
  for (int t = 0; t < 8; ++t) {
    const s8v b = *(const s8v*)(wpack + ((wave * 8 + t) * 64 + lane) * 8);
    acc = __builtin_amdgcn_mfma_f32_16x16x32_bf16(a[t], b, acc, 0, 0, 0);
  }

  const float ob = outb2[16 * wave + cl];
  float xv[4];
#pragma unroll
  for (int r = 0; r < 4; ++r) {
    const float v = acc[r] + ob;
    xv[r] = v;
    float p1 = v, p2 = v * v;
#pragma unroll
    for (int off = 1; off < 16; off <<= 1) {
      p1 += __shfl_xor(p1, off, 64);
      p2 += __shfl_xor(p2, off, 64);
    }
    if (cl == 0) {
      part[wave][quad * 4 + r][0] = p1;
      part[wave][quad * 4 + r][1] = p2;
    }
  }
  __syncthreads();
#pragma unroll
  for (int r = 0; r < 4; ++r) {
    const int row = quad * 4 + r;
    const float t1 = part[0][row][0] + part[1][row][0] +
                     part[2][row][0] + part[3][row][0];
    const float t2 = part[0][row][1] + part[1][row][1] +
                     part[2][row][1] + part[3][row][1];
    const float mu = t1 * (1.f / 64.f);
    const float var = t2 * (1.f / 64.f) - mu * mu;
    const float inv = rsqrtf(var + LN_EPS);
    const int c = 16 * wave + cl;
    out[(size_t)(n0 + row) * FF + c] = (xv[r] - mu) * inv * ln_g[c] + ln_b[c];
  }
}

// ---------------- launch ---------------------------------------------------
extern "C" void kernel_launch(void* const* d_in, const int* in_sizes, int n_in,
                              void* d_out, int out_size, void* d_ws,
                              size_t ws_size, hipStream_t stream) {
  const float* h_in   = (const float*)d_in[0];
  const int*   src    = (const int*)d_in[1];
  const int*   dst    = (const int*)d_in[2];
  const float* fc_w   = (const float*)d_in[3];
  const float* attn_l = (const float*)d_in[4];
  const float* attn_r = (const float*)d_in[5];
  const float* gbias  = (const float*)d_in[6];
  const float* out_w  = (const float*)d_in[7];
  const float* out_b  = (const float*)d_in[8];
  const float* ln_g   = (const float*)d_in[9];
  const float* ln_b   = (const float*)d_in[10];
  float* out = (float*)d_out;

  char* p = (char*)d_ws;
  auto alloc = [&](size_t bytes) {
    char* q = p;
    p += (bytes + 255) & ~(size_t)255;
    return q;
  };
  unsigned short* hb     = (unsigned short*)alloc((size_t)NN * FF * 2); // 6.4 MB
  unsigned short* wpack  = (unsigned short*)alloc((size_t)WPACK_N * 2);
  float* alv     = (float*)alloc(256 * 4);
  float* arv     = (float*)alloc(256 * 4);
  float* outb2   = (float*)alloc(64 * 4);
  float* el      = (float*)alloc((size_t)NN * HH * 4);
  float* er      = (float*)alloc((size_t)NN * HH * 4);
  int*   cnt8    = (int*)alloc((size_t)NXCD * NN * 4);                  // 1.6 MB
  unsigned short* colp8 =
      (unsigned short*)alloc((size_t)NXCD * NN * RCAP * 2);             // 25.6 MB

  k_prep<<<(NXCD * NN + 255) / 256, 256, 0, stream>>>(
      fc_w, out_w, attn_l, attn_r, gbias, out_b, wpack, alv, arv, outb2, cnt8);
  k_elr<<<(NN + 31) / 32, 256, 0, stream>>>(h_in, alv, arv, hb, el, er);
  k_scatter<<<(EE + 255) / 256, 256, 0, stream>>>(src, dst, cnt8, colp8);
  k_gather_out<<<NTILE, 256, 0, stream>>>(hb, el, er, cnt8, colp8, wpack,
                                          outb2, ln_g, ln_b, out);
}